// Round 3
// baseline (76.324 us; speedup 1.0000x reference)
//
#include <hip/hip_runtime.h>

// ROI pooling, image-band-stationary decomposition.
// img: (200,200,256) f32 NHWC; rois: (2000,4) int32 (x,y,w,h); out: (2000,7,7,256) f32.
//
// Key fact: for each (roi, py) pair, the two source rows are ylo and yhi<=ylo+1.
// So binning pairs by band(ylo) with a 1-row halo makes each band self-contained.
// Band+halo = 14 rows x 200 x 256 x 4B = 2.8 MB < 4 MB per-XCD L2. Band b is
// processed entirely on XCD (b&7) (blockIdx round-robin heuristic), so each image
// row is fetched from HBM into exactly one L2, ~once.

#define BH     13              // band height (rows of ylo per band)
#define NBANDS 16              // ceil(199/13) = 16
#define NXCD   8

// ---- Kernel A: bin the R*7 (roi,py) pairs by band, lay out per-XCD ----------
// hdr layout in d_ws (ints): [0..7]=xcd_start, [8..15]=xcd_count, [16..] = perm
__global__ __launch_bounds__(256) void roi_bin_kernel(
    const int* __restrict__ rois, int R, int* __restrict__ hdr)
{
    __shared__ int cnt[NBANDS];
    __shared__ int off[NBANDS];

    const int tid   = threadIdx.x;
    const int pairs = R * 7;
    int* perm = hdr + 16;

    if (tid < NBANDS) cnt[tid] = 0;
    __syncthreads();

    // histogram of band(ylo)
    for (int p = tid; p < pairs; p += 256) {
        const int r  = p / 7;
        const int py = p - r * 7;
        const int y  = rois[4 * r + 1];
        const int h  = rois[4 * r + 3];
        const float ty = ((float)py + 0.5f) * ((float)h / 7.0f) - 0.5f;
        const int  iy  = (int)floorf(ty);
        const int  ylo = min(max(iy, 0), h - 1) + y;
        atomicAdd(&cnt[ylo / BH], 1);
    }
    __syncthreads();

    // thread 0: per-XCD region starts; band b goes to XCD b&7 (b, then b+8)
    if (tid == 0) {
        int xstart[NXCD];
        int acc = 0;
        for (int x = 0; x < NXCD; ++x) {
            xstart[x] = acc;
            const int c = cnt[x] + cnt[x + 8];
            hdr[x]     = acc;   // xcd_start
            hdr[8 + x] = c;     // xcd_count
            acc += c;
        }
        for (int b = 0; b < NBANDS; ++b)
            off[b] = xstart[b & 7] + (b >= 8 ? cnt[b - 8] : 0);
    }
    __syncthreads();

    // scatter pair ids into perm (order within band arbitrary; output invariant)
    for (int p = tid; p < pairs; p += 256) {
        const int r  = p / 7;
        const int py = p - r * 7;
        const int y  = rois[4 * r + 1];
        const int h  = rois[4 * r + 3];
        const float ty = ((float)py + 0.5f) * ((float)h / 7.0f) - 0.5f;
        const int  iy  = (int)floorf(ty);
        const int  ylo = min(max(iy, 0), h - 1) + y;
        const int  pos = atomicAdd(&off[ylo / BH], 1);
        perm[pos] = p;
    }
}

// ---- Kernel B: one (roi,py) pair per block iteration ------------------------
__global__ __launch_bounds__(256) void roi_band_kernel(
    const float* __restrict__ img,
    const int*   __restrict__ rois,
    const int*   __restrict__ hdr,
    float*       __restrict__ out)
{
    constexpr int P = 7;
    constexpr int C = 256;
    constexpr int W = 200;

    const int xcd    = blockIdx.x & 7;           // round-robin XCD heuristic
    const int nslots = gridDim.x >> 3;
    const int start  = hdr[xcd];
    const int count  = hdr[8 + xcd];
    const int* perm  = hdr + 16;

    const int wv = threadIdx.x >> 6;             // 4 waves/block
    const int c  = (threadIdx.x & 63) << 2;      // 4 channels/lane

    for (int rank = blockIdx.x >> 3; rank < count; rank += nslots) {
        const int p  = perm[start + rank];
        const int r  = p / 7;
        const int py = p - r * 7;

        const int x = rois[4 * r + 0];
        const int y = rois[4 * r + 1];
        const int w = rois[4 * r + 2];
        const int h = rois[4 * r + 3];

        const float sy = (float)h / (float)P;
        const float ty = ((float)py + 0.5f) * sy - 0.5f;
        const float fy = floorf(ty);
        const float wy = ty - fy;
        const int   iy = (int)fy;
        const int   ylo = min(max(iy,     0), h - 1) + y;
        const int   yhi = min(max(iy + 1, 0), h - 1) + y;

        const float* row0 = img + (long)ylo * W * C;
        const float* row1 = img + (long)yhi * W * C;
        const float sx = (float)w / (float)P;

        float* out_row = out + ((long)r * P + py) * P * C;

        for (int px = wv; px < P; px += 4) {
            const float tx = ((float)px + 0.5f) * sx - 0.5f;
            const float fx = floorf(tx);
            const float wx = tx - fx;
            const int   ix = (int)fx;
            const int   xlo = min(max(ix,     0), w - 1) + x;
            const int   xhi = min(max(ix + 1, 0), w - 1) + x;

            const float4 v00 = *(const float4*)(row0 + xlo * C + c);
            const float4 v01 = *(const float4*)(row0 + xhi * C + c);
            const float4 v10 = *(const float4*)(row1 + xlo * C + c);
            const float4 v11 = *(const float4*)(row1 + xhi * C + c);

            float4 res;
            {
                float t0 = v00.x + (v01.x - v00.x) * wx;
                float b0 = v10.x + (v11.x - v10.x) * wx;
                res.x = t0 + (b0 - t0) * wy;
                float t1 = v00.y + (v01.y - v00.y) * wx;
                float b1 = v10.y + (v11.y - v10.y) * wx;
                res.y = t1 + (b1 - t1) * wy;
                float t2 = v00.z + (v01.z - v00.z) * wx;
                float b2 = v10.z + (v11.z - v10.z) * wx;
                res.z = t2 + (b2 - t2) * wy;
                float t3 = v00.w + (v01.w - v00.w) * wx;
                float b3 = v10.w + (v11.w - v10.w) * wx;
                res.w = t3 + (b3 - t3) * wy;
            }

            *(float4*)(out_row + px * C + c) = res;
        }
    }
}

extern "C" void kernel_launch(void* const* d_in, const int* in_sizes, int n_in,
                              void* d_out, int out_size, void* d_ws, size_t ws_size,
                              hipStream_t stream) {
    const float* img  = (const float*)d_in[0];
    const int*   rois = (const int*)d_in[1];
    float*       out  = (float*)d_out;
    int*         hdr  = (int*)d_ws;

    const int R     = in_sizes[1] / 4;        // 2000 ROIs
    const int pairs = R * 7;                  // 14000 (roi,py) pairs
    const int slots = (pairs + NXCD - 1) / NXCD;
    const int grid  = slots * NXCD;

    roi_bin_kernel<<<1, 256, 0, stream>>>(rois, R, hdr);
    roi_band_kernel<<<grid, 256, 0, stream>>>(img, rois, hdr, out);
}

// Round 4
// 65.617 us; speedup vs baseline: 1.1632x; 1.1632x over previous
//
#include <hip/hip_runtime.h>

// ROI pooling: bilinear resize each (h,w) crop to 7x7 over 256 channels.
// img: (200,200,256) f32 NHWC; rois: (2000,4) int32 (x,y,w,h); out: (2000,7,7,256) f32.
// One 64-lane wave per output cell (roi,py,px); each lane does 4 channels (float4).
// Output stores are non-temporal so the 98 MB stream doesn't evict the 41 MB
// image from L2/L3 (R3 finding: FETCH_SIZE was 4x the image size).

typedef float f32x4 __attribute__((ext_vector_type(4)));

__global__ __launch_bounds__(256) void roi_pool_kernel(
    const float* __restrict__ img,
    const int*   __restrict__ rois,
    float*       __restrict__ out,
    int ncells)
{
    constexpr int P = 7;
    constexpr int C = 256;
    constexpr int W = 200;

    const int cell = blockIdx.x * 4 + (threadIdx.x >> 6);   // 4 waves/block, 1 cell/wave
    if (cell >= ncells) return;
    const int c = (threadIdx.x & 63) * 4;                   // channel (x4 per lane)

    const int px = cell % P;
    const int py = (cell / P) % P;
    const int r  = cell / (P * P);

    const int x = rois[4 * r + 0];
    const int y = rois[4 * r + 1];
    const int w = rois[4 * r + 2];
    const int h = rois[4 * r + 3];

    // Axis samples (tf.image.resize bilinear half-pixel semantics), f32 like ref.
    const float sy = (float)h / (float)P;
    const float ty = ((float)py + 0.5f) * sy - 0.5f;
    const float fy = floorf(ty);
    const float wy = ty - fy;
    const int   iy = (int)fy;
    const int   ylo = min(max(iy,     0), h - 1) + y;
    const int   yhi = min(max(iy + 1, 0), h - 1) + y;

    const float sx = (float)w / (float)P;
    const float tx = ((float)px + 0.5f) * sx - 0.5f;
    const float fx = floorf(tx);
    const float wx = tx - fx;
    const int   ix = (int)fx;
    const int   xlo = min(max(ix,     0), w - 1) + x;
    const int   xhi = min(max(ix + 1, 0), w - 1) + x;

    const float* row0 = img + (long)ylo * W * C;
    const float* row1 = img + (long)yhi * W * C;

    const f32x4 v00 = *(const f32x4*)(row0 + xlo * C + c);
    const f32x4 v01 = *(const f32x4*)(row0 + xhi * C + c);
    const f32x4 v10 = *(const f32x4*)(row1 + xlo * C + c);
    const f32x4 v11 = *(const f32x4*)(row1 + xhi * C + c);

    const f32x4 top = v00 + (v01 - v00) * wx;
    const f32x4 bot = v10 + (v11 - v10) * wx;
    const f32x4 res = top + (bot - top) * wy;

    __builtin_nontemporal_store(res, (f32x4*)(out + (long)cell * C + c));
}

extern "C" void kernel_launch(void* const* d_in, const int* in_sizes, int n_in,
                              void* d_out, int out_size, void* d_ws, size_t ws_size,
                              hipStream_t stream) {
    const float* img  = (const float*)d_in[0];
    const int*   rois = (const int*)d_in[1];
    float*       out  = (float*)d_out;

    const int R      = in_sizes[1] / 4;   // 2000
    const int ncells = R * 7 * 7;         // 98000
    const int blocks = (ncells + 3) / 4;  // 4 cells (waves) per block

    roi_pool_kernel<<<blocks, 256, 0, stream>>>(img, rois, out, ncells);
}

// Round 5
// 62.410 us; speedup vs baseline: 1.2230x; 1.0514x over previous
//
#include <hip/hip_runtime.h>

// ROI pooling: bilinear resize each (h,w) crop to 7x7 over 256 channels.
// img: (200,200,256) f32 NHWC; rois: (2000,4) int32 (x,y,w,h); out: (2000,7,7,256) f32.
// One 64-lane wave per output cell (roi,py,px); each lane does 4 channels (float4).
// - NT stores: 98 MB output stream bypasses L2/L3 allocation (R4: +2%).
// - Bijective XCD-chunked blockIdx swizzle (m204): each XCD gets a contiguous
//   chunk of cells, so a whole ROI's 13 blocks run on ONE XCD back-to-back and
//   intra-ROI row reuse (py-neighbors share source rows) hits that L2 instead
//   of being split across 8 incoherent L2s by the default round-robin dispatch.

typedef float f32x4 __attribute__((ext_vector_type(4)));

__global__ __launch_bounds__(256) void roi_pool_kernel(
    const float* __restrict__ img,
    const int*   __restrict__ rois,
    float*       __restrict__ out,
    int ncells)
{
    constexpr int P = 7;
    constexpr int C = 256;
    constexpr int W = 200;

    // --- bijective XCD-chunk swizzle: orig -> logical (contiguous per XCD) ---
    const int nwg  = gridDim.x;
    const int q    = nwg >> 3;
    const int rr   = nwg & 7;
    const int xcd  = blockIdx.x & 7;
    const int base = (xcd < rr) ? xcd * (q + 1) : rr * (q + 1) + (xcd - rr) * q;
    const int bid  = base + (blockIdx.x >> 3);

    const int cell = bid * 4 + (threadIdx.x >> 6);   // 4 waves/block, 1 cell/wave
    if (cell >= ncells) return;
    const int c = (threadIdx.x & 63) * 4;            // channel (x4 per lane)

    const int px = cell % P;
    const int py = (cell / P) % P;
    const int r  = cell / (P * P);

    const int x = rois[4 * r + 0];
    const int y = rois[4 * r + 1];
    const int w = rois[4 * r + 2];
    const int h = rois[4 * r + 3];

    // Axis samples (tf.image.resize bilinear half-pixel semantics), f32 like ref.
    const float sy = (float)h / (float)P;
    const float ty = ((float)py + 0.5f) * sy - 0.5f;
    const float fy = floorf(ty);
    const float wy = ty - fy;
    const int   iy = (int)fy;
    const int   ylo = min(max(iy,     0), h - 1) + y;
    const int   yhi = min(max(iy + 1, 0), h - 1) + y;

    const float sx = (float)w / (float)P;
    const float tx = ((float)px + 0.5f) * sx - 0.5f;
    const float fx = floorf(tx);
    const float wx = tx - fx;
    const int   ix = (int)fx;
    const int   xlo = min(max(ix,     0), w - 1) + x;
    const int   xhi = min(max(ix + 1, 0), w - 1) + x;

    const float* row0 = img + (long)ylo * W * C;
    const float* row1 = img + (long)yhi * W * C;

    const f32x4 v00 = *(const f32x4*)(row0 + xlo * C + c);
    const f32x4 v01 = *(const f32x4*)(row0 + xhi * C + c);
    const f32x4 v10 = *(const f32x4*)(row1 + xlo * C + c);
    const f32x4 v11 = *(const f32x4*)(row1 + xhi * C + c);

    const f32x4 top = v00 + (v01 - v00) * wx;
    const f32x4 bot = v10 + (v11 - v10) * wx;
    const f32x4 res = top + (bot - top) * wy;

    __builtin_nontemporal_store(res, (f32x4*)(out + (long)cell * C + c));
}

extern "C" void kernel_launch(void* const* d_in, const int* in_sizes, int n_in,
                              void* d_out, int out_size, void* d_ws, size_t ws_size,
                              hipStream_t stream) {
    const float* img  = (const float*)d_in[0];
    const int*   rois = (const int*)d_in[1];
    float*       out  = (float*)d_out;

    const int R      = in_sizes[1] / 4;   // 2000
    const int ncells = R * 7 * 7;         // 98000
    const int blocks = (ncells + 3) / 4;  // 4 cells (waves) per block

    roi_pool_kernel<<<blocks, 256, 0, stream>>>(img, rois, out, ncells);
}

// Round 6
// 47.119 us; speedup vs baseline: 1.6198x; 1.3245x over previous
//
#include <hip/hip_runtime.h>

// ROI pooling: bilinear resize each (h,w) crop to 7x7 over 256 channels.
// img: (200,200,256) f32 NHWC; rois: (2000,4) int32 (x,y,w,h); out: (2000,7,7,256) f32.
//
// R6 structure: each (roi,py) "pair" reads exactly 2 image rows {ylo, ylo+1}.
// K1 counting-sorts the 14000 pairs by ylo (200 bins, LDS atomics, 1 block).
// K2 processes pairs in sorted order, 2 pairs per 256-thread block, with a
// bijective XCD-chunked swizzle: each XCD walks a contiguous run of sorted
// pairs, so its instantaneous image footprint is ~20 rows (~4 MB = one L2)
// and each image row is fetched from HBM ~once instead of ~4x (R5: FETCH
// 158 MB vs 41 MB compulsory was cross-ROI reuse scattered in time).
// Output values are per-pair and independent of sort order -> deterministic.

typedef float f32x4 __attribute__((ext_vector_type(4)));

// ---- K1: counting sort of pairs by ylo into perm (d_ws) ---------------------
__global__ __launch_bounds__(1024) void roi_sort_kernel(
    const int* __restrict__ rois, int R, int* __restrict__ perm)
{
    __shared__ int cnt[256];
    __shared__ int cur[256];
    const int tid   = threadIdx.x;
    const int pairs = R * 7;

    if (tid < 256) cnt[tid] = 0;
    __syncthreads();

    for (int p = tid; p < pairs; p += 1024) {
        const int r  = p / 7;
        const int py = p - r * 7;
        const int y  = rois[4 * r + 1];
        const int h  = rois[4 * r + 3];
        const float ty = ((float)py + 0.5f) * ((float)h / 7.0f) - 0.5f;
        const int  iy  = (int)floorf(ty);
        const int  ylo = min(max(iy, 0), h - 1) + y;   // in [0,199]
        atomicAdd(&cnt[ylo], 1);
    }
    __syncthreads();

    if (tid == 0) {                 // exclusive scan over 200 bins
        int acc = 0;
        for (int b = 0; b < 256; ++b) { cur[b] = acc; acc += cnt[b]; }
    }
    __syncthreads();

    for (int p = tid; p < pairs; p += 1024) {
        const int r  = p / 7;
        const int py = p - r * 7;
        const int y  = rois[4 * r + 1];
        const int h  = rois[4 * r + 3];
        const float ty = ((float)py + 0.5f) * ((float)h / 7.0f) - 0.5f;
        const int  iy  = (int)floorf(ty);
        const int  ylo = min(max(iy, 0), h - 1) + y;
        const int  pos = atomicAdd(&cur[ylo], 1);
        perm[pos] = p;
    }
}

// ---- K2: main kernel, 2 sorted pairs per block ------------------------------
__global__ __launch_bounds__(256) void roi_pool_kernel(
    const float* __restrict__ img,
    const int*   __restrict__ rois,
    const int*   __restrict__ perm,
    float*       __restrict__ out)
{
    constexpr int P = 7;
    constexpr int C = 256;
    constexpr int W = 200;

    // bijective XCD-chunk swizzle (m204): each XCD owns a contiguous chunk
    const int nwg  = gridDim.x;
    const int q    = nwg >> 3;
    const int rr   = nwg & 7;
    const int xcd  = blockIdx.x & 7;
    const int base = (xcd < rr) ? xcd * (q + 1) : rr * (q + 1) + (xcd - rr) * q;
    const int bid  = base + (blockIdx.x >> 3);

    const int wave = threadIdx.x >> 6;
    const int c    = (threadIdx.x & 63) << 2;

    // load + precompute both pairs' state
    const float* row0v[2]; const float* row1v[2];
    float wyv[2], sxv[2];
    int   xv[2], wv_[2];
    long  obase[2];

    #pragma unroll
    for (int pp = 0; pp < 2; ++pp) {
        const int p  = perm[2 * bid + pp];
        const int r  = p / 7;
        const int py = p - r * 7;

        const int x = rois[4 * r + 0];
        const int y = rois[4 * r + 1];
        const int w = rois[4 * r + 2];
        const int h = rois[4 * r + 3];

        const float ty = ((float)py + 0.5f) * ((float)h / (float)P) - 0.5f;
        const float fy = floorf(ty);
        const int   iy = (int)fy;
        const int   ylo = min(max(iy,     0), h - 1) + y;
        const int   yhi = min(max(iy + 1, 0), h - 1) + y;

        row0v[pp] = img + (long)ylo * W * C;
        row1v[pp] = img + (long)yhi * W * C;
        wyv[pp]   = ty - fy;
        sxv[pp]   = (float)w / (float)P;
        xv[pp]    = x;
        wv_[pp]   = w;
        obase[pp] = ((long)r * P + py) * P * C;
    }

    // 14 cells over 4 waves: waves take {4,4,3,3}
    for (int cell = wave; cell < 2 * P; cell += 4) {
        const int pp = (cell >= P) ? 1 : 0;
        const int px = cell - P * pp;

        const float* row0 = row0v[pp];
        const float* row1 = row1v[pp];
        const float wy = wyv[pp];
        const float sx = sxv[pp];
        const int   x  = xv[pp];
        const int   w  = wv_[pp];

        const float tx = ((float)px + 0.5f) * sx - 0.5f;
        const float fx = floorf(tx);
        const float wx = tx - fx;
        const int   ix = (int)fx;
        const int   xlo = min(max(ix,     0), w - 1) + x;
        const int   xhi = min(max(ix + 1, 0), w - 1) + x;

        const f32x4 v00 = *(const f32x4*)(row0 + xlo * C + c);
        const f32x4 v01 = *(const f32x4*)(row0 + xhi * C + c);
        const f32x4 v10 = *(const f32x4*)(row1 + xlo * C + c);
        const f32x4 v11 = *(const f32x4*)(row1 + xhi * C + c);

        const f32x4 top = v00 + (v01 - v00) * wx;
        const f32x4 bot = v10 + (v11 - v10) * wx;
        const f32x4 res = top + (bot - top) * wy;

        __builtin_nontemporal_store(res, (f32x4*)(out + obase[pp] + px * C + c));
    }
}

extern "C" void kernel_launch(void* const* d_in, const int* in_sizes, int n_in,
                              void* d_out, int out_size, void* d_ws, size_t ws_size,
                              hipStream_t stream) {
    const float* img  = (const float*)d_in[0];
    const int*   rois = (const int*)d_in[1];
    float*       out  = (float*)d_out;
    int*         perm = (int*)d_ws;

    const int R      = in_sizes[1] / 4;   // 2000
    const int npairs = R * 7;             // 14000
    const int blocks = npairs / 2;        // 7000 (2 pairs per block)

    roi_sort_kernel<<<1, 1024, 0, stream>>>(rois, R, perm);
    roi_pool_kernel<<<blocks, 256, 0, stream>>>(img, rois, perm, out);
}

// Round 7
// 46.384 us; speedup vs baseline: 1.6455x; 1.0159x over previous
//
#include <hip/hip_runtime.h>

// ROI pooling: bilinear resize each (h,w) crop to 7x7 over 256 channels.
// img: (200,200,256) f32 NHWC; rois: (2000,4) int32 (x,y,w,h); out: (2000,7,7,256) f32.
//
// Structure (R7):
//  K1: counting-sort the 14000 (roi,py) pairs by source row ylo (200 bins).
//  K2: one pair per 64-lane wave, 4 consecutive sorted pairs per block,
//      bijective XCD-chunked swizzle -> each XCD walks a contiguous run of
//      sorted pairs; instantaneous image footprint ~few rows -> L2-resident.
//      px-loop has compile-time bound 7 -> fully unrolled, 28 independent
//      loads in flight per wave (R6 was 4 -> latency-bound).
//  NT stores keep the 98 MB output stream from evicting the image.

typedef float f32x4 __attribute__((ext_vector_type(4)));

// ---- K1: counting sort of pairs by ylo into perm (d_ws) ---------------------
__global__ __launch_bounds__(1024) void roi_sort_kernel(
    const int* __restrict__ rois, int R, int* __restrict__ perm)
{
    __shared__ int cnt[256];
    __shared__ int cur[256];
    const int tid   = threadIdx.x;
    const int pairs = R * 7;

    if (tid < 256) cnt[tid] = 0;
    __syncthreads();

    for (int p = tid; p < pairs; p += 1024) {
        const int r  = p / 7;
        const int py = p - r * 7;
        const int y  = rois[4 * r + 1];
        const int h  = rois[4 * r + 3];
        const float ty = ((float)py + 0.5f) * ((float)h / 7.0f) - 0.5f;
        const int  iy  = (int)floorf(ty);
        const int  ylo = min(max(iy, 0), h - 1) + y;   // in [0,199]
        atomicAdd(&cnt[ylo], 1);
    }
    __syncthreads();

    if (tid == 0) {                 // exclusive scan over 200 bins
        int acc = 0;
        for (int b = 0; b < 256; ++b) { cur[b] = acc; acc += cnt[b]; }
    }
    __syncthreads();

    for (int p = tid; p < pairs; p += 1024) {
        const int r  = p / 7;
        const int py = p - r * 7;
        const int y  = rois[4 * r + 1];
        const int h  = rois[4 * r + 3];
        const float ty = ((float)py + 0.5f) * ((float)h / 7.0f) - 0.5f;
        const int  iy  = (int)floorf(ty);
        const int  ylo = min(max(iy, 0), h - 1) + y;
        const int  pos = atomicAdd(&cur[ylo], 1);
        perm[pos] = p;
    }
}

// ---- K2: main kernel, 1 sorted pair per wave, 4 per block -------------------
__global__ __launch_bounds__(256) void roi_pool_kernel(
    const float* __restrict__ img,
    const int*   __restrict__ rois,
    const int*   __restrict__ perm,
    float*       __restrict__ out,
    int npairs)
{
    constexpr int P = 7;
    constexpr int C = 256;
    constexpr int W = 200;

    // bijective XCD-chunk swizzle (m204): each XCD owns a contiguous chunk
    const int nwg  = gridDim.x;
    const int q    = nwg >> 3;
    const int rr   = nwg & 7;
    const int xcd  = blockIdx.x & 7;
    const int base = (xcd < rr) ? xcd * (q + 1) : rr * (q + 1) + (xcd - rr) * q;
    const int bid  = base + (blockIdx.x >> 3);

    const int wave = threadIdx.x >> 6;
    const int c    = (threadIdx.x & 63) << 2;      // 4 channels/lane

    const int pidx = bid * 4 + wave;
    if (pidx >= npairs) return;

    const int p  = perm[pidx];
    const int r  = p / 7;
    const int py = p - r * 7;

    const int x = rois[4 * r + 0];
    const int y = rois[4 * r + 1];
    const int w = rois[4 * r + 2];
    const int h = rois[4 * r + 3];

    const float ty = ((float)py + 0.5f) * ((float)h / (float)P) - 0.5f;
    const float fy = floorf(ty);
    const float wy = ty - fy;
    const int   iy = (int)fy;
    const int   ylo = min(max(iy,     0), h - 1) + y;
    const int   yhi = min(max(iy + 1, 0), h - 1) + y;

    const float* row0 = img + (long)ylo * W * C + c;
    const float* row1 = img + (long)yhi * W * C + c;
    const float  sx   = (float)w / (float)P;

    float* out_row = out + ((long)r * P + py) * P * C + c;

    #pragma unroll
    for (int px = 0; px < P; ++px) {
        const float tx = ((float)px + 0.5f) * sx - 0.5f;
        const float fx = floorf(tx);
        const float wx = tx - fx;
        const int   ix = (int)fx;
        const int   xlo = min(max(ix,     0), w - 1) + x;
        const int   xhi = min(max(ix + 1, 0), w - 1) + x;

        const f32x4 v00 = *(const f32x4*)(row0 + xlo * C);
        const f32x4 v01 = *(const f32x4*)(row0 + xhi * C);
        const f32x4 v10 = *(const f32x4*)(row1 + xlo * C);
        const f32x4 v11 = *(const f32x4*)(row1 + xhi * C);

        const f32x4 top = v00 + (v01 - v00) * wx;
        const f32x4 bot = v10 + (v11 - v10) * wx;
        const f32x4 res = top + (bot - top) * wy;

        __builtin_nontemporal_store(res, (f32x4*)(out_row + px * C));
    }
}

extern "C" void kernel_launch(void* const* d_in, const int* in_sizes, int n_in,
                              void* d_out, int out_size, void* d_ws, size_t ws_size,
                              hipStream_t stream) {
    const float* img  = (const float*)d_in[0];
    const int*   rois = (const int*)d_in[1];
    float*       out  = (float*)d_out;
    int*         perm = (int*)d_ws;

    const int R      = in_sizes[1] / 4;   // 2000
    const int npairs = R * 7;             // 14000
    const int blocks = (npairs + 3) / 4;  // 3500 (1 pair per wave, 4 waves/block)

    roi_sort_kernel<<<1, 1024, 0, stream>>>(rois, R, perm);
    roi_pool_kernel<<<blocks, 256, 0, stream>>>(img, rois, perm, out, npairs);
}